// Round 9
// baseline (241.916 us; speedup 1.0000x reference)
//
#include <hip/hip_runtime.h>
#include <math.h>

#define T_SEQ 2048
#define D_MODEL 2048
#define HEAD_DIM 64
#define N_HEADS 32
#define N_KV 8

using short8 = __attribute__((ext_vector_type(8))) short;
using f32x4  = __attribute__((ext_vector_type(4))) float;

#define MFMA16(a, b, c) __builtin_amdgcn_mfma_f32_16x16x32_bf16(a, b, c, 0, 0, 0)

__device__ __forceinline__ unsigned short f2bf(float f) {
    unsigned int u = __builtin_bit_cast(unsigned int, f);
    u += 0x7fff + ((u >> 16) & 1);
    return (unsigned short)(u >> 16);
}
__device__ __forceinline__ void gld_lds16(const ushort* g, ushort* l) {
    __builtin_amdgcn_global_load_lds((const __attribute__((address_space(1))) void*)g,
                                     (__attribute__((address_space(3))) void*)l, 16, 0, 0);
}

// ---------------------------------------------------------------------------
// Fused cast (5 fp32->bf16 tensors) + RoPE table build (llama3 scaling).
// Blocks [0,14336): float4 casts. Blocks [14336,14592): rope tables,
// fp32 transposed [i][T].
// ---------------------------------------------------------------------------
__global__ __launch_bounds__(256) void cast_rope_kernel(
    const float* __restrict__ x, const float* __restrict__ wq,
    const float* __restrict__ wk, const float* __restrict__ wv,
    const float* __restrict__ wo,
    ushort* __restrict__ xb, ushort* __restrict__ wqb,
    ushort* __restrict__ wkb, ushort* __restrict__ wvb, ushort* __restrict__ wob,
    float* __restrict__ cosT, float* __restrict__ sinT,
    const int* __restrict__ start_pos, int T) {
    int bid = blockIdx.x;
    if (bid < 14336) {
        int i = bid * 256 + threadIdx.x;
        const float* src; ushort* dst; int off;
        if (i < 1048576)      { src = x;  dst = xb;  off = i; }
        else if (i < 2097152) { src = wq; dst = wqb; off = i - 1048576; }
        else if (i < 2359296) { src = wk; dst = wkb; off = i - 2097152; }
        else if (i < 2621440) { src = wv; dst = wvb; off = i - 2359296; }
        else                  { src = wo; dst = wob; off = i - 2621440; }
        float4 v = ((const float4*)src)[off];
        ushort4 o;
        o.x = f2bf(v.x); o.y = f2bf(v.y); o.z = f2bf(v.z); o.w = f2bf(v.w);
        ((ushort4*)dst)[off] = o;
    } else {
        int gid = (bid - 14336) * 256 + threadIdx.x;
        int t = gid >> 5;
        int i = gid & 31;
        float pos = (float)(start_pos[0] + t);
        float expo = (float)i / 32.0f;
        float inv_freq = 1.0f / powf(500000.0f, expo);
        const float two_pi = 6.283185307179586f;
        float wavelen = two_pi / inv_freq;
        const float low_wl = 8192.0f;
        const float high_wl = 2048.0f;
        float inv;
        if (wavelen > low_wl) {
            inv = inv_freq / 32.0f;
        } else if (wavelen < high_wl) {
            inv = inv_freq;
        } else {
            float smooth = (8192.0f / wavelen - 1.0f) / 3.0f;
            inv = (1.0f - smooth) * (inv_freq / 32.0f) + smooth * inv_freq;
        }
        float ang = pos * inv;
        cosT[i * T + t] = cosf(ang);
        sinT[i * T + t] = sinf(ang);
    }
}

// ---------------------------------------------------------------------------
// Fused QKV GEMM + RoPE epilogue. 64x128 tile, BK=64 as 2x BK=32 sub-tiles
// per barrier, dbuf, XOR-swizzled. Grid 32 x 24 = 768 blocks (3/CU).
// grid.y: 0..15 Q, 16..19 K, 20..23 V(transposed)
// ---------------------------------------------------------------------------
__global__ __launch_bounds__(256) void gemm_qkv(
    const ushort* __restrict__ X, const ushort* __restrict__ Wqb,
    const ushort* __restrict__ Wkb, const ushort* __restrict__ Wvb,
    ushort* __restrict__ Qo, ushort* __restrict__ Ko, ushort* __restrict__ Vto,
    const float* __restrict__ cosT, const float* __restrict__ sinT,
    int T, int D) {
    __shared__ __align__(16) ushort As[2][2][2048];   // [buf][sub][64x32]
    __shared__ __align__(16) ushort Bs[2][2][4096];   // [buf][sub][128x32]
    const int tid = threadIdx.x;
    const int w = tid >> 6, l = tid & 63;
    const int m0 = blockIdx.x * 64;
    const int n0g = blockIdx.y * 128;

    const ushort* B;
    ushort* Cout;
    int n0, doRope;
    if (n0g < 2048)      { B = Wqb + (size_t)n0g * D;          Cout = Qo;  n0 = n0g;        doRope = 1; }
    else if (n0g < 2560) { B = Wkb + (size_t)(n0g - 2048) * D; Cout = Ko;  n0 = n0g - 2048; doRope = 1; }
    else                 { B = Wvb + (size_t)(n0g - 2560) * D; Cout = Vto; n0 = n0g - 2560; doRope = 0; }

    const int wm = (w >> 1) * 32, wn = (w & 1) * 64;
    const int lr = l & 15;
    const int quad = l >> 4;

    f32x4 zero = {0.f, 0.f, 0.f, 0.f};
    f32x4 acc[2][4];
#pragma unroll
    for (int i = 0; i < 2; ++i)
#pragma unroll
        for (int j = 0; j < 4; ++j) acc[i][j] = zero;

    const int srow = l >> 2;                       // 0..15
    const int scg  = ((l & 3) ^ (srow & 3)) * 8;   // swizzled global chunk
    const ushort* Ag  = X + (size_t)(m0 + 16 * w + srow) * D + scg;
    const ushort* Bg0 = B + (size_t)(16 * (2 * w) + srow) * D + scg;
    const ushort* Bg1 = B + (size_t)(16 * (2 * w + 1) + srow) * D + scg;

#define GSTAGE(k0v, nb) { \
    gld_lds16(Ag  + (k0v),      &As[nb][0][w * 512]); \
    gld_lds16(Ag  + (k0v) + 32, &As[nb][1][w * 512]); \
    gld_lds16(Bg0 + (k0v),      &Bs[nb][0][(2 * w) * 512]); \
    gld_lds16(Bg0 + (k0v) + 32, &Bs[nb][1][(2 * w) * 512]); \
    gld_lds16(Bg1 + (k0v),      &Bs[nb][0][(2 * w + 1) * 512]); \
    gld_lds16(Bg1 + (k0v) + 32, &Bs[nb][1][(2 * w + 1) * 512]); }

    GSTAGE(0, 0);

    const int rsw = (quad ^ (lr & 3)) * 8;
    for (int k0 = 0; k0 < D; k0 += 64) {
        const int b = (k0 >> 6) & 1;
        __syncthreads();
        if (k0 + 64 < D) GSTAGE(k0 + 64, b ^ 1);
#pragma unroll
        for (int sub = 0; sub < 2; ++sub) {
            short8 af[2], bf[4];
#pragma unroll
            for (int i = 0; i < 2; ++i) af[i] = *(const short8*)&As[b][sub][(wm + i * 16 + lr) * 32 + rsw];
#pragma unroll
            for (int j = 0; j < 4; ++j) bf[j] = *(const short8*)&Bs[b][sub][(wn + j * 16 + lr) * 32 + rsw];
#pragma unroll
            for (int i = 0; i < 2; ++i)
#pragma unroll
                for (int j = 0; j < 4; ++j)
                    acc[i][j] = MFMA16(af[i], bf[j], acc[i][j]);
        }
    }
#undef GSTAGE

    const int mbase = m0 + wm + quad * 4;
    if (doRope) {
#pragma unroll
        for (int i = 0; i < 2; ++i) {
            int trow = mbase + i * 16;
#pragma unroll
            for (int j = 0; j < 2; ++j) {
                int i1 = lr + j * 16;
                float4 c4 = *(const float4*)&cosT[(size_t)i1 * T + trow];
                float4 s4 = *(const float4*)&sinT[(size_t)i1 * T + trow];
                int n1 = n0 + wn + lr + j * 16;
                int n2 = n1 + 32;
                size_t b1 = (size_t)(n1 >> 6) * ((size_t)T * 64) + (size_t)(n1 & 63);
                size_t b2 = (size_t)(n2 >> 6) * ((size_t)T * 64) + (size_t)(n2 & 63);
                float cs[4] = {c4.x, c4.y, c4.z, c4.w};
                float sn[4] = {s4.x, s4.y, s4.z, s4.w};
#pragma unroll
                for (int r = 0; r < 4; ++r) {
                    float x1 = acc[i][j][r], x2 = acc[i][j + 2][r];
                    Cout[b1 + (size_t)(trow + r) * 64] = f2bf(x1 * cs[r] - x2 * sn[r]);
                    Cout[b2 + (size_t)(trow + r) * 64] = f2bf(x2 * cs[r] + x1 * sn[r]);
                }
            }
        }
    } else {
#pragma unroll
        for (int i = 0; i < 2; ++i)
#pragma unroll
            for (int j = 0; j < 4; ++j) {
                int n = n0 + wn + lr + j * 16;
                int m = mbase + i * 16;
                ushort4 o;
                o.x = f2bf(acc[i][j][0]); o.y = f2bf(acc[i][j][1]);
                o.z = f2bf(acc[i][j][2]); o.w = f2bf(acc[i][j][3]);
                *(ushort4*)&Vto[(size_t)n * T + m] = o;
            }
    }
}

// ---------------------------------------------------------------------------
// Output projection GEMM (C fp32), same BK=64 dual-sub-tile core
// ---------------------------------------------------------------------------
__global__ __launch_bounds__(256) void gemm_bt_f32(const ushort* __restrict__ A,
                                                   const ushort* __restrict__ B,
                                                   float* __restrict__ C,
                                                   int M, int N, int K) {
    __shared__ __align__(16) ushort As[2][2][2048];
    __shared__ __align__(16) ushort Bs[2][2][4096];
    const int tid = threadIdx.x;
    const int w = tid >> 6, l = tid & 63;
    const int m0 = blockIdx.x * 64, n0 = blockIdx.y * 128;
    const int wm = (w >> 1) * 32, wn = (w & 1) * 64;
    const int lr = l & 15;
    const int quad = l >> 4;

    f32x4 zero = {0.f, 0.f, 0.f, 0.f};
    f32x4 acc[2][4];
#pragma unroll
    for (int i = 0; i < 2; ++i)
#pragma unroll
        for (int j = 0; j < 4; ++j) acc[i][j] = zero;

    const int srow = l >> 2;
    const int scg  = ((l & 3) ^ (srow & 3)) * 8;
    const ushort* Ag  = A + (size_t)(m0 + 16 * w + srow) * K + scg;
    const ushort* Bg0 = B + (size_t)(n0 + 16 * (2 * w) + srow) * K + scg;
    const ushort* Bg1 = B + (size_t)(n0 + 16 * (2 * w + 1) + srow) * K + scg;

#define GSTAGE(k0v, nb) { \
    gld_lds16(Ag  + (k0v),      &As[nb][0][w * 512]); \
    gld_lds16(Ag  + (k0v) + 32, &As[nb][1][w * 512]); \
    gld_lds16(Bg0 + (k0v),      &Bs[nb][0][(2 * w) * 512]); \
    gld_lds16(Bg0 + (k0v) + 32, &Bs[nb][1][(2 * w) * 512]); \
    gld_lds16(Bg1 + (k0v),      &Bs[nb][0][(2 * w + 1) * 512]); \
    gld_lds16(Bg1 + (k0v) + 32, &Bs[nb][1][(2 * w + 1) * 512]); }

    GSTAGE(0, 0);

    const int rsw = (quad ^ (lr & 3)) * 8;
    for (int k0 = 0; k0 < K; k0 += 64) {
        const int b = (k0 >> 6) & 1;
        __syncthreads();
        if (k0 + 64 < K) GSTAGE(k0 + 64, b ^ 1);
#pragma unroll
        for (int sub = 0; sub < 2; ++sub) {
            short8 af[2], bf[4];
#pragma unroll
            for (int i = 0; i < 2; ++i) af[i] = *(const short8*)&As[b][sub][(wm + i * 16 + lr) * 32 + rsw];
#pragma unroll
            for (int j = 0; j < 4; ++j) bf[j] = *(const short8*)&Bs[b][sub][(wn + j * 16 + lr) * 32 + rsw];
#pragma unroll
            for (int i = 0; i < 2; ++i)
#pragma unroll
                for (int j = 0; j < 4; ++j)
                    acc[i][j] = MFMA16(af[i], bf[j], acc[i][j]);
        }
    }
#undef GSTAGE

    const int mbase = m0 + wm + quad * 4;
    const int nbase = n0 + wn + lr;
#pragma unroll
    for (int i = 0; i < 2; ++i)
#pragma unroll
        for (int j = 0; j < 4; ++j)
#pragma unroll
            for (int r = 0; r < 4; ++r)
                C[(size_t)(mbase + i * 16 + r) * N + (nbase + j * 16)] = acc[i][j][r];
}

// ---------------------------------------------------------------------------
// Flash attention: one 64-row q-tile per block, grid (32,32) = 1024 blocks
// (3/CU co-resident by LDS, 4/CU oversubscribed -> greedy balance + latency
// hiding). qt = 31-bx: heavy blocks dispatch first. 4 waves x 16 q-rows,
// S^T = K@Q^T (Q in regs), XOR-swizzled dbuf K/V (32 KB), Ps stride 72.
// ---------------------------------------------------------------------------
__global__ __launch_bounds__(256) void attn_mfma(const ushort* __restrict__ Q,
                                                 const ushort* __restrict__ K,
                                                 const ushort* __restrict__ Vt,
                                                 ushort* __restrict__ ctx, int T) {
    __shared__ __align__(16) ushort Ks[2][4096];   // [key64][dim64] swizzled
    __shared__ __align__(16) ushort Vs[2][4096];   // [dim64][key64] swizzled
    __shared__ __align__(16) ushort Ps[4][1152];   // per-wave [qrow16][key64] stride 72
    const int tid = threadIdx.x, w = tid >> 6, l = tid & 63;
    const int lr = l & 15, quad = l >> 4;
    const int h = blockIdx.y, hk = h >> 2;
    const ushort* Kb = K + (size_t)hk * T * 64;
    const ushort* Vb = Vt + (size_t)hk * 64 * T;

    const int srow = l >> 3;                    // 0..7
    const int sc   = ((l & 7) ^ srow) * 8;      // swizzled global chunk offset
    const int si0 = 2 * w, si1 = 2 * w + 1;
    const int swz = lr & 7;
    f32x4 zero = {0.f, 0.f, 0.f, 0.f};

    const int qt = 31 - (int)blockIdx.x;        // heavy q-tiles dispatch first
    const int qbase = qt * 64;
    const int qrow_abs = qbase + w * 16 + lr;
    const int ntiles = qt + 1;

    // Q B-fragments in registers for the whole kernel
    short8 qf[2];
#pragma unroll
    for (int ks = 0; ks < 2; ++ks)
        qf[ks] = *(const short8*)(Q + ((size_t)h * T + qbase + w * 16 + lr) * 64 + ks * 32 + quad * 8);

    f32x4 oacc[4];
#pragma unroll
    for (int dj = 0; dj < 4; ++dj) oacc[dj] = zero;
    float lsum = 0.f;

    // prologue: stage tile 0 into buf 0 (identical row math to in-loop staging)
    gld_lds16(Kb + (size_t)(8 * si0 + srow) * 64 + sc, &Ks[0][si0 * 512]);
    gld_lds16(Kb + (size_t)(8 * si1 + srow) * 64 + sc, &Ks[0][si1 * 512]);
    gld_lds16(Vb + (size_t)(8 * si0 + srow) * T + sc, &Vs[0][si0 * 512]);
    gld_lds16(Vb + (size_t)(8 * si1 + srow) * T + sc, &Vs[0][si1 * 512]);

    for (int kt = 0; kt < ntiles; ++kt) {
        const int b = kt & 1;
        __syncthreads();
        if (kt + 1 < ntiles) {
            const int k0n = (kt + 1) * 64;
            gld_lds16(Kb + (size_t)(k0n + 8 * si0 + srow) * 64 + sc, &Ks[b ^ 1][si0 * 512]);
            gld_lds16(Kb + (size_t)(k0n + 8 * si1 + srow) * 64 + sc, &Ks[b ^ 1][si1 * 512]);
            gld_lds16(Vb + (size_t)(8 * si0 + srow) * T + k0n + sc, &Vs[b ^ 1][si0 * 512]);
            gld_lds16(Vb + (size_t)(8 * si1 + srow) * T + k0n + sc, &Vs[b ^ 1][si1 * 512]);
        }
        const int k0 = kt * 64;

        // S^T = K @ Q^T : D[m=key][n=qrow(16)]
        f32x4 s[4];
#pragma unroll
        for (int mi = 0; mi < 4; ++mi) s[mi] = zero;
#pragma unroll
        for (int ks = 0; ks < 2; ++ks)
#pragma unroll
            for (int mi = 0; mi < 4; ++mi) {
                short8 kf = *(const short8*)&Ks[b][(mi * 16 + lr) * 64 + ((4 * ks + quad) ^ swz) * 8];
                s[mi] = MFMA16(kf, qf[ks], s[mi]);
            }

        // exp (+ mask on diagonal tile) -> Ps (ushort4 = 4 consecutive keys)
        const bool masked = (kt == qt);
#pragma unroll
        for (int mi = 0; mi < 4; ++mi) {
            float pv[4];
#pragma unroll
            for (int r = 0; r < 4; ++r) {
                float p = __expf(s[mi][r] * 0.125f);
                if (masked && (k0 + mi * 16 + quad * 4 + r > qrow_abs)) p = 0.f;
                lsum += p;
                pv[r] = p;
            }
            ushort4 pk;
            pk.x = f2bf(pv[0]); pk.y = f2bf(pv[1]); pk.z = f2bf(pv[2]); pk.w = f2bf(pv[3]);
            *(ushort4*)&Ps[w][lr * 72 + mi * 16 + quad * 4] = pk;
        }

        // O += P @ V^T : A = P[qrow][key] rows, B = Vt[dim][key] rows
#pragma unroll
        for (int ks2 = 0; ks2 < 2; ++ks2) {
            short8 pf = *(const short8*)&Ps[w][lr * 72 + ks2 * 32 + quad * 8];
#pragma unroll
            for (int dj = 0; dj < 4; ++dj) {
                short8 vf = *(const short8*)&Vs[b][(dj * 16 + lr) * 64 + ((4 * ks2 + quad) ^ swz) * 8];
                oacc[dj] = MFMA16(pf, vf, oacc[dj]);
            }
        }
    }

    // denominator: reduce over quads (keys); lane (q,lr) holds partial for qrow lr
    float v = lsum;
    v += __shfl_xor(v, 16, 64);
    v += __shfl_xor(v, 32, 64);
    float invr[4];
#pragma unroll
    for (int r = 0; r < 4; ++r)
        invr[r] = 1.f / __shfl(v, quad * 4 + r, 64);

    // write ctx [t][2048] bf16; O C-layout: row=quad*4+r (qrow), col=lr (dim)
#pragma unroll
    for (int dj = 0; dj < 4; ++dj) {
        int col = h * 64 + dj * 16 + lr;
#pragma unroll
        for (int r = 0; r < 4; ++r) {
            int row = qbase + w * 16 + quad * 4 + r;
            ctx[(size_t)row * 2048 + col] = f2bf(oacc[dj][r] * invr[r]);
        }
    }
}

// ---------------------------------------------------------------------------
extern "C" void kernel_launch(void* const* d_in, const int* in_sizes, int n_in,
                              void* d_out, int out_size, void* d_ws, size_t ws_size,
                              hipStream_t stream) {
    const float* x  = (const float*)d_in[0];
    const float* Wq = (const float*)d_in[1];
    const float* Wk = (const float*)d_in[2];
    const float* Wv = (const float*)d_in[3];
    const float* Wo = (const float*)d_in[4];
    const int* start_pos = (const int*)d_in[5];
    float* out = (float*)d_out;

    const int T = T_SEQ, D = D_MODEL;
    const int KV = N_KV * HEAD_DIM;  // 512

    char* w = (char*)d_ws;
    float* cosT = (float*)w;            w += (size_t)32 * T * 4;
    float* sinT = (float*)w;            w += (size_t)32 * T * 4;
    ushort* xbf  = (ushort*)w;          w += (size_t)T * D * 2;     // aliased: ctx
    ushort* wqbf = (ushort*)w;          w += (size_t)D * D * 2;
    ushort* wkbf = (ushort*)w;          w += (size_t)KV * D * 2;
    ushort* wvbf = (ushort*)w;          w += (size_t)KV * D * 2;
    ushort* wobf = (ushort*)w;          w += (size_t)D * D * 2;
    ushort* qbf  = (ushort*)w;          w += (size_t)N_HEADS * T * 64 * 2;
    ushort* kbf  = (ushort*)w;          w += (size_t)N_KV * T * 64 * 2;
    ushort* vtbf = (ushort*)w;          w += (size_t)N_KV * 64 * T * 2;
    ushort* ctxbf = xbf;  // x fully consumed by gemm_qkv before attn writes ctx

    cast_rope_kernel<<<dim3(14592), dim3(256), 0, stream>>>(
        x, Wq, Wk, Wv, Wo, xbf, wqbf, wkbf, wvbf, wobf, cosT, sinT, start_pos, T);

    gemm_qkv<<<dim3(T / 64, (D + 2 * KV) / 128), dim3(256), 0, stream>>>(
        xbf, wqbf, wkbf, wvbf, qbf, kbf, vtbf, cosT, sinT, T, D);

    attn_mfma<<<dim3(32, N_HEADS), dim3(256), 0, stream>>>(qbf, kbf, vtbf, ctxbf, T);

    gemm_bt_f32<<<dim3(T / 64, D / 128), dim3(256), 0, stream>>>(ctxbf, wobf, out, T, D, D);
}